// Round 15
// baseline (299.761 us; speedup 1.0000x reference)
//
#include <hip/hip_runtime.h>
#include <math.h>

#define N1T 65536
#define N2T 16384
#define BSZ 8
#define N1B 8192   // points per batch in xyz1
#define N2B 2048   // points per batch in xyz2
#define C1 256
#define C2 512
#define K1 768     // C1 + C2
#define HID 256
#define BN_EPS 1e-5f
#define NSPLIT 4   // knn ref-interval splits

typedef short bf16x8 __attribute__((ext_vector_type(8)));
typedef float f32x4 __attribute__((ext_vector_type(4)));

// Exact single-rounded f32 ops via ISA — immune to -ffast-math / contraction.
__device__ __forceinline__ float mul_rn(float a, float b) {
    float r; asm("v_mul_f32 %0, %1, %2" : "=v"(r) : "v"(a), "v"(b)); return r;
}
__device__ __forceinline__ float add_rn(float a, float b) {
    float r; asm("v_add_f32 %0, %1, %2" : "=v"(r) : "v"(a), "v"(b)); return r;
}
__device__ __forceinline__ float sub_rn(float a, float b) {
    float r; asm("v_sub_f32 %0, %1, %2" : "=v"(r) : "v"(a), "v"(b)); return r;
}
__device__ __forceinline__ float fma_rn(float a, float b, float c) {
    float r; asm("v_fma_f32 %0, %1, %2, %3" : "=v"(r) : "v"(a), "v"(b), "v"(c)); return r;
}
// SGPR-operand variants (src0 = scalar): refs are wave-uniform in knn_scan.
// Commutativity of IEEE mul/add keeps results bit-identical to v,v forms.
__device__ __forceinline__ float mul_sv(float s, float v) {
    float r; asm("v_mul_f32 %0, %1, %2" : "=v"(r) : "s"(s), "v"(v)); return r;
}
__device__ __forceinline__ float fma_svv(float s, float v, float c) {
    float r; asm("v_fma_f32 %0, %1, %2, %3" : "=v"(r) : "s"(s), "v"(v), "v"(c)); return r;
}
__device__ __forceinline__ float add_sv(float s, float v) {
    float r; asm("v_add_f32 %0, %1, %2" : "=v"(r) : "s"(s), "v"(v)); return r;
}
// f32 -> bf16 round-to-nearest-even
__device__ __forceinline__ short f2bf(float f) {
    unsigned u = __builtin_bit_cast(unsigned, f);
    u += 0x7fffu + ((u >> 16) & 1u);
    return (short)(u >> 16);
}
// bf16 -> f32 (exact)
__device__ __forceinline__ float bf2f(short s) {
    return __builtin_bit_cast(float, ((unsigned)(unsigned short)s) << 16);
}

// ---------------------------------------------------------------- KNN-3
// FROZEN arithmetic (r9): d2 = (qq - 2*dot) + kk, nofma qq/kk, fma-asc dot.
// r15 restructure: 1 query/lane, refs streamed through SGPRs (wave-uniform
// scalar loads — no LDS in the loop). 4-way ref split for TLP (4096 waves,
// 4/SIMD). Partial top-3 per split; merge kernel applies the r11/r12-
// validated lexicographic (d, idx) merge == sequential strict-< scan.

// prep: ref4[p] = (x, y, z, kk) with frozen kk rounding
__global__ __launch_bounds__(256) void ref_prep_kernel(
    const float* __restrict__ xyz2, float4* __restrict__ ref4)
{
    const int p = blockIdx.x * 256 + threadIdx.x;
    float x = xyz2[3 * p], y = xyz2[3 * p + 1], z = xyz2[3 * p + 2];
    float kk = add_rn(add_rn(mul_rn(x, x), mul_rn(y, y)), mul_rn(z, z));
    ref4[p] = make_float4(x, y, z, kk);
}

__global__ __launch_bounds__(256) void knn_scan_kernel(
    const float* __restrict__ xyz1, const float4* __restrict__ ref4,
    float* __restrict__ pd, int* __restrict__ pj)
{
    const int tid = threadIdx.x;
    const int qg = blockIdx.x & 255;         // query group (256 queries)
    const int sp = blockIdx.x >> 8;          // split 0..3 (512 refs each)
    const int q = qg * 256 + tid;
    const int batch = (qg * 256) / N1B;      // uniform expression -> s_load refs
    const float4* refs = ref4 + (size_t)batch * N2B + sp * 512;

    const float qx = xyz1[q * 3 + 0], qy = xyz1[q * 3 + 1], qz = xyz1[q * 3 + 2];
    const float qq = add_rn(add_rn(mul_rn(qx, qx), mul_rn(qy, qy)), mul_rn(qz, qz));

    const int gb = sp * 512;                 // global-within-batch index base
    float a0 = 1e30f, a1 = 1e30f, a2 = 1e30f;
    int   ai0 = 0x7fffffff, ai1 = 0x7fffffff, ai2 = 0x7fffffff;
    float c0 = 1e30f, c1 = 1e30f, c2 = 1e30f;
    int   ci0 = 0x7fffffff, ci1 = 0x7fffffff, ci2 = 0x7fffffff;
#pragma unroll 4
    for (int jj = 0; jj < 256; ++jj) {
        float4 rA = refs[jj];                // wave-uniform -> SGPRs
        float4 rB = refs[jj + 256];
        {
            float p0 = mul_sv(rA.x, qx);
            float dt = fma_svv(rA.z, qz, fma_svv(rA.y, qy, p0));
            float d  = add_sv(rA.w, sub_rn(qq, add_rn(dt, dt)));
            const int j = gb + jj;
            bool lt2 = d < a2, lt1 = d < a1, lt0 = d < a0;
            a2 = lt1 ? a1 : (lt2 ? d : a2); ai2 = lt1 ? ai1 : (lt2 ? j : ai2);
            a1 = lt0 ? a0 : (lt1 ? d : a1); ai1 = lt0 ? ai0 : (lt1 ? j : ai1);
            a0 = lt0 ? d : a0;              ai0 = lt0 ? j : ai0;
        }
        {
            float p0 = mul_sv(rB.x, qx);
            float dt = fma_svv(rB.z, qz, fma_svv(rB.y, qy, p0));
            float d  = add_sv(rB.w, sub_rn(qq, add_rn(dt, dt)));
            const int j = gb + 256 + jj;
            bool lt2 = d < c2, lt1 = d < c1, lt0 = d < c0;
            c2 = lt1 ? c1 : (lt2 ? d : c2); ci2 = lt1 ? ci1 : (lt2 ? j : ci2);
            c1 = lt0 ? c0 : (lt1 ? d : c1); ci1 = lt0 ? ci0 : (lt1 ? j : ci1);
            c0 = lt0 ? d : c0;              ci0 = lt0 ? j : ci0;
        }
    }
    // merge the two streams lexicographically by (d, idx)
    float bd0 = a0, bd1 = a1, bd2 = a2;
    int   bi0 = ai0, bi1 = ai1, bi2 = ai2;
#define LEXINS(d, ji)                                                        \
    if ((d < bd2) || (d == bd2 && ji < bi2)) {                               \
        if ((d < bd1) || (d == bd1 && ji < bi1)) {                           \
            bd2 = bd1; bi2 = bi1;                                            \
            if ((d < bd0) || (d == bd0 && ji < bi0)) {                       \
                bd1 = bd0; bi1 = bi0; bd0 = d; bi0 = ji;                     \
            } else { bd1 = d; bi1 = ji; }                                    \
        } else { bd2 = d; bi2 = ji; }                                        \
    }
    LEXINS(c0, ci0) LEXINS(c1, ci1) LEXINS(c2, ci2)
#undef LEXINS
    const size_t pb = ((size_t)sp * N1T + q) * 3;
    pd[pb + 0] = bd0; pd[pb + 1] = bd1; pd[pb + 2] = bd2;
    pj[pb + 0] = bi0; pj[pb + 1] = bi1; pj[pb + 2] = bi2;
}

__global__ __launch_bounds__(256) void knn_merge_kernel(
    const float* __restrict__ pd, const int* __restrict__ pj,
    int* __restrict__ idx_out, float* __restrict__ w_out)
{
    const int q = blockIdx.x * 256 + threadIdx.x;
    float bd0 = 1e30f, bd1 = 1e30f, bd2 = 1e30f;
    int   bi0 = 0x7fffffff, bi1 = 0x7fffffff, bi2 = 0x7fffffff;
#define LEXINS(d, ji)                                                        \
    if ((d < bd2) || (d == bd2 && ji < bi2)) {                               \
        if ((d < bd1) || (d == bd1 && ji < bi1)) {                           \
            bd2 = bd1; bi2 = bi1;                                            \
            if ((d < bd0) || (d == bd0 && ji < bi0)) {                       \
                bd1 = bd0; bi1 = bi0; bd0 = d; bi0 = ji;                     \
            } else { bd1 = d; bi1 = ji; }                                    \
        } else { bd2 = d; bi2 = ji; }                                        \
    }
#pragma unroll
    for (int sp = 0; sp < NSPLIT; ++sp) {
        const size_t pb = ((size_t)sp * N1T + q) * 3;
#pragma unroll
        for (int k = 0; k < 3; ++k) {
            float d = pd[pb + k];
            int   j = pj[pb + k];
            LEXINS(d, j)
        }
    }
#undef LEXINS
    // frozen weight arithmetic (r9)
    float d0s = __fsqrt_rn(fmaxf(bd0, 0.0f));
    float d1s = __fsqrt_rn(fmaxf(bd1, 0.0f));
    float d2s = __fsqrt_rn(fmaxf(bd2, 0.0f));
    float r0 = __fdiv_rn(1.0f, add_rn(d0s, 1e-8f));
    float r1 = __fdiv_rn(1.0f, add_rn(d1s, 1e-8f));
    float r2 = __fdiv_rn(1.0f, add_rn(d2s, 1e-8f));
    float rs = add_rn(add_rn(r0, r1), r2);
    w_out[q * 3 + 0] = __fdiv_rn(r0, rs);
    w_out[q * 3 + 1] = __fdiv_rn(r1, rs);
    w_out[q * 3 + 2] = __fdiv_rn(r2, rs);
    const int batch = q >> 13;               // q / N1B
    idx_out[q * 3 + 0] = batch * N2B + bi0;
    idx_out[q * 3 + 1] = batch * N2B + bi1;
    idx_out[q * 3 + 2] = batch * N2B + bi2;
}

// ------------------------------- IDW gather + points1 cast (fused A build)
// abuf[N1][768]: cols 0:256 = bf16(points1), cols 256:768 = interp (bf16)
__global__ __launch_bounds__(128) void interp_kernel(
    const float* __restrict__ points1, const short* __restrict__ p2b,
    const int* __restrict__ idx, const float* __restrict__ w,
    short* __restrict__ abuf)
{
    const int row = blockIdx.x;
    const int t = threadIdx.x;
    // points1 cast: threads 0..63 each handle 4 f32 -> 4 bf16
    if (t < 64) {
        float4 u = ((const float4*)(points1 + (size_t)row * C1))[t];
        short4 o; o.x = f2bf(u.x); o.y = f2bf(u.y); o.z = f2bf(u.z); o.w = f2bf(u.w);
        *(short4*)(abuf + (size_t)row * K1 + t * 4) = o;
    }
    // interp: all 128 threads, 4 cols each
    const int j0 = idx[row * 3 + 0], j1 = idx[row * 3 + 1], j2 = idx[row * 3 + 2];
    const float w0 = w[row * 3 + 0], w1 = w[row * 3 + 1], w2 = w[row * 3 + 2];
    short4 a4 = *(const short4*)(p2b + (size_t)j0 * C2 + t * 4);
    short4 b4 = *(const short4*)(p2b + (size_t)j1 * C2 + t * 4);
    short4 d4 = *(const short4*)(p2b + (size_t)j2 * C2 + t * 4);
    short4 o4;
    o4.x = f2bf(fmaf(bf2f(a4.x), w0, fmaf(bf2f(b4.x), w1, bf2f(d4.x) * w2)));
    o4.y = f2bf(fmaf(bf2f(a4.y), w0, fmaf(bf2f(b4.y), w1, bf2f(d4.y) * w2)));
    o4.z = f2bf(fmaf(bf2f(a4.z), w0, fmaf(bf2f(b4.z), w1, bf2f(d4.z) * w2)));
    o4.w = f2bf(fmaf(bf2f(a4.w), w0, fmaf(bf2f(b4.w), w1, bf2f(d4.w) * w2)));
    *(short4*)(abuf + (size_t)row * K1 + C1 + t * 4) = o4;
}

// ------------------------------------------------------ prep kernels
// points2 f32 -> bf16 flat
__global__ __launch_bounds__(256) void cast_p2_kernel(
    const float* __restrict__ p2, short* __restrict__ p2b)
{
    const size_t i = ((size_t)blockIdx.x * 256 + threadIdx.x) * 8;
    float4 u0 = *(const float4*)(p2 + i);
    float4 u1 = *(const float4*)(p2 + i + 4);
    bf16x8 v;
    v[0] = f2bf(u0.x); v[1] = f2bf(u0.y); v[2] = f2bf(u0.z); v[3] = f2bf(u0.w);
    v[4] = f2bf(u1.x); v[5] = f2bf(u1.y); v[6] = f2bf(u1.z); v[7] = f2bf(u1.w);
    *(bf16x8*)(p2b + i) = v;
}

// W[K][N] f32 -> WT[N][K] bf16
__global__ __launch_bounds__(256) void transpose_w_kernel(
    const float* __restrict__ Win, short* __restrict__ WT, int K, int N)
{
    const int e = blockIdx.x * 256 + threadIdx.x;
    const int k = e / N, n = e % N;
    WT[(size_t)n * K + k] = f2bf(Win[e]);
}

// --------------------------------------------- bf16 MFMA GEMMs (128x128 tile)
#define LDP 40

#define GEMM_EPILOGUE(STORE_STMT)                                             \
    __shared__ float redS[2][2][64], redQ[2][2][64];                          \
    _Pragma("unroll")                                                         \
    for (int n = 0; n < 4; ++n) {                                             \
        const int col = col0 + wc * 64 + n * 16 + l16;                        \
        const float bv = bias[col];                                           \
        float s = 0.f, qa = 0.f;                                              \
        _Pragma("unroll")                                                     \
        for (int m = 0; m < 4; ++m) {                                         \
            const int rowb = row0 + wr * 64 + m * 16 + (lane >> 4) * 4;       \
            _Pragma("unroll")                                                 \
            for (int j = 0; j < 4; ++j) {                                     \
                float v = acc[m][n][j] + bv;                                  \
                STORE_STMT;                                                   \
                s += v; qa = fmaf(v, v, qa);                                  \
            }                                                                 \
        }                                                                     \
        s += __shfl_xor(s, 16, 64);  s += __shfl_xor(s, 32, 64);              \
        qa += __shfl_xor(qa, 16, 64); qa += __shfl_xor(qa, 32, 64);           \
        if ((lane >> 4) == 0) {                                               \
            redS[wr][wc][n * 16 + l16] = s;                                   \
            redQ[wr][wc][n * 16 + l16] = qa;                                  \
        }                                                                     \
    }                                                                         \
    __syncthreads();                                                          \
    if (tid < 128) {                                                          \
        const int wcf = tid >> 6, cf = tid & 63;                              \
        float s = redS[0][wcf][cf] + redS[1][wcf][cf];                        \
        float qa = redQ[0][wcf][cf] + redQ[1][wcf][cf];                       \
        const int gcol = col0 + wcf * 64 + cf;                                \
        psum[(size_t)blockIdx.y * HID + gcol] = s;                            \
        psq[(size_t)blockIdx.y * HID + gcol] = qa;                            \
    }

// y1b = bf16( abuf @ W1 + b1 ), stats from f32 acc
__global__ __launch_bounds__(256) void gemm1m_kernel(
    const short* __restrict__ abuf, const short* __restrict__ w1t,
    const float* __restrict__ bias, short* __restrict__ y1b,
    float* __restrict__ psum, float* __restrict__ psq)
{
    __shared__ short As[128][LDP];
    __shared__ short Bs[128][LDP];
    const int tid = threadIdx.x;
    const int lane = tid & 63, wv = tid >> 6;
    const int wr = wv >> 1, wc = wv & 1;
    const int l16 = lane & 15, kh = (lane >> 4) * 8;
    const int row0 = blockIdx.y * 128, col0 = blockIdx.x * 128;
    f32x4 acc[4][4];
#pragma unroll
    for (int m = 0; m < 4; ++m)
#pragma unroll
        for (int n = 0; n < 4; ++n) acc[m][n] = (f32x4){0.f, 0.f, 0.f, 0.f};

    const int c0 = tid * 2;
    const int r0c = c0 >> 2, kc0 = (c0 & 3) * 8;
    const int r1c = (c0 + 1) >> 2, kc1 = ((c0 + 1) & 3) * 8;

    for (int kt = 0; kt < K1 / 32; ++kt) {
        const int k0 = kt * 32;
        bf16x8 va = *(const bf16x8*)(abuf + (size_t)(row0 + r0c) * K1 + k0 + kc0);
        bf16x8 vb = *(const bf16x8*)(abuf + (size_t)(row0 + r1c) * K1 + k0 + kc1);
        bf16x8 wa = *(const bf16x8*)(w1t + (size_t)(col0 + r0c) * K1 + k0 + kc0);
        bf16x8 wb = *(const bf16x8*)(w1t + (size_t)(col0 + r1c) * K1 + k0 + kc1);
        __syncthreads();
        *(bf16x8*)(&As[r0c][kc0]) = va;
        *(bf16x8*)(&As[r1c][kc1]) = vb;
        *(bf16x8*)(&Bs[r0c][kc0]) = wa;
        *(bf16x8*)(&Bs[r1c][kc1]) = wb;
        __syncthreads();

        bf16x8 af[4], bf[4];
#pragma unroll
        for (int m = 0; m < 4; ++m)
            af[m] = *(const bf16x8*)(&As[wr * 64 + m * 16 + l16][kh]);
#pragma unroll
        for (int n = 0; n < 4; ++n)
            bf[n] = *(const bf16x8*)(&Bs[wc * 64 + n * 16 + l16][kh]);
#pragma unroll
        for (int m = 0; m < 4; ++m)
#pragma unroll
            for (int n = 0; n < 4; ++n)
                acc[m][n] = __builtin_amdgcn_mfma_f32_16x16x32_bf16(
                    af[m], bf[n], acc[m][n], 0, 0, 0);
    }
    GEMM_EPILOGUE(y1b[(size_t)(rowb + j) * HID + col] = f2bf(v))
}

// y2b = bf16( relu(bn(y1b)) @ W2 + b2 ), stats from f32 acc
__global__ __launch_bounds__(256) void gemm2m_kernel(
    const short* __restrict__ y1b, const float* __restrict__ scale,
    const float* __restrict__ shift, const short* __restrict__ w2t,
    const float* __restrict__ bias, short* __restrict__ y2b,
    float* __restrict__ psum, float* __restrict__ psq)
{
    __shared__ short As[128][LDP];
    __shared__ short Bs[128][LDP];
    const int tid = threadIdx.x;
    const int lane = tid & 63, wv = tid >> 6;
    const int wr = wv >> 1, wc = wv & 1;
    const int l16 = lane & 15, kh = (lane >> 4) * 8;
    const int row0 = blockIdx.y * 128, col0 = blockIdx.x * 128;
    f32x4 acc[4][4];
#pragma unroll
    for (int m = 0; m < 4; ++m)
#pragma unroll
        for (int n = 0; n < 4; ++n) acc[m][n] = (f32x4){0.f, 0.f, 0.f, 0.f};

    const int c0 = tid * 2;
    const int r0c = c0 >> 2, kc0 = (c0 & 3) * 8;
    const int r1c = (c0 + 1) >> 2, kc1 = ((c0 + 1) & 3) * 8;

    for (int kt = 0; kt < HID / 32; ++kt) {
        const int k0 = kt * 32;
        bf16x8 x0 = *(const bf16x8*)(y1b + (size_t)(row0 + r0c) * HID + k0 + kc0);
        bf16x8 x1 = *(const bf16x8*)(y1b + (size_t)(row0 + r1c) * HID + k0 + kc1);
        float4 s0 = *(const float4*)(scale + k0 + kc0);
        float4 s1 = *(const float4*)(scale + k0 + kc0 + 4);
        float4 h0 = *(const float4*)(shift + k0 + kc0);
        float4 h1 = *(const float4*)(shift + k0 + kc0 + 4);
        float4 s2 = *(const float4*)(scale + k0 + kc1);
        float4 s3 = *(const float4*)(scale + k0 + kc1 + 4);
        float4 h2 = *(const float4*)(shift + k0 + kc1);
        float4 h3 = *(const float4*)(shift + k0 + kc1 + 4);
        bf16x8 va, vb;
        va[0] = f2bf(fmaxf(fmaf(bf2f(x0[0]), s0.x, h0.x), 0.f));
        va[1] = f2bf(fmaxf(fmaf(bf2f(x0[1]), s0.y, h0.y), 0.f));
        va[2] = f2bf(fmaxf(fmaf(bf2f(x0[2]), s0.z, h0.z), 0.f));
        va[3] = f2bf(fmaxf(fmaf(bf2f(x0[3]), s0.w, h0.w), 0.f));
        va[4] = f2bf(fmaxf(fmaf(bf2f(x0[4]), s1.x, h1.x), 0.f));
        va[5] = f2bf(fmaxf(fmaf(bf2f(x0[5]), s1.y, h1.y), 0.f));
        va[6] = f2bf(fmaxf(fmaf(bf2f(x0[6]), s1.z, h1.z), 0.f));
        va[7] = f2bf(fmaxf(fmaf(bf2f(x0[7]), s1.w, h1.w), 0.f));
        vb[0] = f2bf(fmaxf(fmaf(bf2f(x1[0]), s2.x, h2.x), 0.f));
        vb[1] = f2bf(fmaxf(fmaf(bf2f(x1[1]), s2.y, h2.y), 0.f));
        vb[2] = f2bf(fmaxf(fmaf(bf2f(x1[2]), s2.z, h2.z), 0.f));
        vb[3] = f2bf(fmaxf(fmaf(bf2f(x1[3]), s2.w, h2.w), 0.f));
        vb[4] = f2bf(fmaxf(fmaf(bf2f(x1[4]), s3.x, h3.x), 0.f));
        vb[5] = f2bf(fmaxf(fmaf(bf2f(x1[5]), s3.y, h3.y), 0.f));
        vb[6] = f2bf(fmaxf(fmaf(bf2f(x1[6]), s3.z, h3.z), 0.f));
        vb[7] = f2bf(fmaxf(fmaf(bf2f(x1[7]), s3.w, h3.w), 0.f));
        bf16x8 wa = *(const bf16x8*)(w2t + (size_t)(col0 + r0c) * HID + k0 + kc0);
        bf16x8 wb = *(const bf16x8*)(w2t + (size_t)(col0 + r1c) * HID + k0 + kc1);
        __syncthreads();
        *(bf16x8*)(&As[r0c][kc0]) = va;
        *(bf16x8*)(&As[r1c][kc1]) = vb;
        *(bf16x8*)(&Bs[r0c][kc0]) = wa;
        *(bf16x8*)(&Bs[r1c][kc1]) = wb;
        __syncthreads();

        bf16x8 af[4], bf[4];
#pragma unroll
        for (int m = 0; m < 4; ++m)
            af[m] = *(const bf16x8*)(&As[wr * 64 + m * 16 + l16][kh]);
#pragma unroll
        for (int n = 0; n < 4; ++n)
            bf[n] = *(const bf16x8*)(&Bs[wc * 64 + n * 16 + l16][kh]);
#pragma unroll
        for (int m = 0; m < 4; ++m)
#pragma unroll
            for (int n = 0; n < 4; ++n)
                acc[m][n] = __builtin_amdgcn_mfma_f32_16x16x32_bf16(
                    af[m], bf[n], acc[m][n], 0, 0, 0);
    }
    GEMM_EPILOGUE(y2b[(size_t)(rowb + j) * HID + col] = f2bf(v))
}

// ----------------------------------------------------- BN finalize (512 rows)
__global__ __launch_bounds__(256) void bn_finalize_kernel(
    const float* __restrict__ psum, const float* __restrict__ psq,
    const float* __restrict__ g, const float* __restrict__ be,
    float* __restrict__ scale, float* __restrict__ shift)
{
    const int c = threadIdx.x;
    float s = 0.0f, q = 0.0f;
    for (int b = 0; b < 512; ++b) { s += psum[b * HID + c]; q += psq[b * HID + c]; }
    const float inv_n = 1.0f / (float)N1T;
    const float mu = s * inv_n;
    const float var = fmaxf(q * inv_n - mu * mu, 0.0f);
    const float sc = g[c] * rsqrtf(var + BN_EPS);
    scale[c] = sc;
    shift[c] = be[c] - mu * sc;
}

// --------------------------------------------------------- final BN+ReLU
__global__ __launch_bounds__(256) void bn_apply_kernel(
    const short* __restrict__ y2b, const float* __restrict__ scale,
    const float* __restrict__ shift, float* __restrict__ out)
{
    const size_t i = ((size_t)blockIdx.x * 256 + threadIdx.x) * 8;
    const int c8 = (int)(i & 255);
    bf16x8 x = *(const bf16x8*)(y2b + i);
    float4 s0 = *(const float4*)(scale + c8);
    float4 s1 = *(const float4*)(scale + c8 + 4);
    float4 h0 = *(const float4*)(shift + c8);
    float4 h1 = *(const float4*)(shift + c8 + 4);
    float4 o0, o1;
    o0.x = fmaxf(fmaf(bf2f(x[0]), s0.x, h0.x), 0.f);
    o0.y = fmaxf(fmaf(bf2f(x[1]), s0.y, h0.y), 0.f);
    o0.z = fmaxf(fmaf(bf2f(x[2]), s0.z, h0.z), 0.f);
    o0.w = fmaxf(fmaf(bf2f(x[3]), s0.w, h0.w), 0.f);
    o1.x = fmaxf(fmaf(bf2f(x[4]), s1.x, h1.x), 0.f);
    o1.y = fmaxf(fmaf(bf2f(x[5]), s1.y, h1.y), 0.f);
    o1.z = fmaxf(fmaf(bf2f(x[6]), s1.z, h1.z), 0.f);
    o1.w = fmaxf(fmaf(bf2f(x[7]), s1.w, h1.w), 0.f);
    *(float4*)(out + i) = o0;
    *(float4*)(out + i + 4) = o1;
}

// -------------------------------------------------------------- launcher
extern "C" void kernel_launch(void* const* d_in, const int* in_sizes, int n_in,
                              void* d_out, int out_size, void* d_ws, size_t ws_size,
                              hipStream_t stream)
{
    const float* xyz1    = (const float*)d_in[0];
    const float* points1 = (const float*)d_in[1];
    const float* xyz2    = (const float*)d_in[2];
    const float* points2 = (const float*)d_in[3];
    const float* W1  = (const float*)d_in[6];
    const float* b1  = (const float*)d_in[7];
    const float* g1  = (const float*)d_in[8];
    const float* be1 = (const float*)d_in[9];
    const float* W2  = (const float*)d_in[10];
    const float* b2  = (const float*)d_in[11];
    const float* g2  = (const float*)d_in[12];
    const float* be2 = (const float*)d_in[13];
    float* out = (float*)d_out;

    char* ws = (char*)d_ws;
    short* abuf = (short*)ws;                          // bf16 [N1][768]
    short* y1b  = (short*)(ws + 100663296);            // bf16 [N1][256]
    short* p2b  = (short*)(ws + 134217728);            // bf16 [N2T][512]
    size_t off  = 134217728 + 16777216;
    short*  w1t    = (short*)(ws + off);  off += (size_t)K1 * HID * 2;
    short*  w2t    = (short*)(ws + off);  off += (size_t)HID * HID * 2;
    float4* ref4   = (float4*)(ws + off); off += (size_t)N2T * 16;
    int*    idx    = (int*)(ws + off);    off += (size_t)N1T * 3 * 4;
    float*  w      = (float*)(ws + off);  off += (size_t)N1T * 3 * 4;
    float*  pd     = (float*)(ws + off);  off += (size_t)NSPLIT * N1T * 3 * 4;
    int*    pj     = (int*)(ws + off);    off += (size_t)NSPLIT * N1T * 3 * 4;
    float*  psum   = (float*)(ws + off);  off += 512 * 256 * 4;
    float*  psq    = (float*)(ws + off);  off += 512 * 256 * 4;
    float*  scale1 = (float*)(ws + off);  off += 256 * 4;
    float*  shift1 = (float*)(ws + off);  off += 256 * 4;
    float*  scale2 = (float*)(ws + off);  off += 256 * 4;
    float*  shift2 = (float*)(ws + off);  off += 256 * 4;
    short* y2b = abuf;  // reuse: abuf dead after gemm1m

    ref_prep_kernel<<<N2T / 256, 256, 0, stream>>>(xyz2, ref4);
    cast_p2_kernel<<<N2T * C2 / 8 / 256, 256, 0, stream>>>(points2, p2b);
    transpose_w_kernel<<<K1 * HID / 256, 256, 0, stream>>>(W1, w1t, K1, HID);
    transpose_w_kernel<<<HID * HID / 256, 256, 0, stream>>>(W2, w2t, HID, HID);
    knn_scan_kernel<<<256 * NSPLIT, 256, 0, stream>>>(xyz1, ref4, pd, pj);
    knn_merge_kernel<<<N1T / 256, 256, 0, stream>>>(pd, pj, idx, w);
    interp_kernel<<<N1T, 128, 0, stream>>>(points1, p2b, idx, w, abuf);
    gemm1m_kernel<<<dim3(HID / 128, N1T / 128), 256, 0, stream>>>(
        abuf, w1t, b1, y1b, psum, psq);
    bn_finalize_kernel<<<1, 256, 0, stream>>>(psum, psq, g1, be1, scale1, shift1);
    gemm2m_kernel<<<dim3(HID / 128, N1T / 128), 256, 0, stream>>>(
        y1b, scale1, shift1, w2t, b2, y2b, psum, psq);
    bn_finalize_kernel<<<1, 256, 0, stream>>>(psum, psq, g2, be2, scale2, shift2);
    bn_apply_kernel<<<N1T * HID / 8 / 256, 256, 0, stream>>>(y2b, scale2, shift2, out);
}

// Round 16
// 274.474 us; speedup vs baseline: 1.0921x; 1.0921x over previous
//
#include <hip/hip_runtime.h>
#include <math.h>

#define N1T 65536
#define N2T 16384
#define BSZ 8
#define N1B 8192   // points per batch in xyz1
#define N2B 2048   // points per batch in xyz2
#define C1 256
#define C2 512
#define K1 768     // C1 + C2
#define HID 256
#define BN_EPS 1e-5f

typedef short bf16x8 __attribute__((ext_vector_type(8)));
typedef float f32x4 __attribute__((ext_vector_type(4)));

// Exact single-rounded f32 ops via ISA — immune to -ffast-math / contraction.
__device__ __forceinline__ float mul_rn(float a, float b) {
    float r; asm("v_mul_f32 %0, %1, %2" : "=v"(r) : "v"(a), "v"(b)); return r;
}
__device__ __forceinline__ float add_rn(float a, float b) {
    float r; asm("v_add_f32 %0, %1, %2" : "=v"(r) : "v"(a), "v"(b)); return r;
}
__device__ __forceinline__ float sub_rn(float a, float b) {
    float r; asm("v_sub_f32 %0, %1, %2" : "=v"(r) : "v"(a), "v"(b)); return r;
}
__device__ __forceinline__ float fma_rn(float a, float b, float c) {
    float r; asm("v_fma_f32 %0, %1, %2, %3" : "=v"(r) : "v"(a), "v"(b), "v"(c)); return r;
}
// f32 -> bf16 round-to-nearest-even
__device__ __forceinline__ short f2bf(float f) {
    unsigned u = __builtin_bit_cast(unsigned, f);
    u += 0x7fffu + ((u >> 16) & 1u);
    return (short)(u >> 16);
}
// bf16 -> f32 (exact)
__device__ __forceinline__ float bf2f(short s) {
    return __builtin_bit_cast(float, ((unsigned)(unsigned short)s) << 16);
}

// ---------------------------------------------------------------- KNN-3
// FROZEN: r13's kernel verbatim — best measured (72.3 µs). d2 arithmetic
// (r9): d2 = (qq - 2*dot) + kk, nofma qq/kk, fma-asc dot. 4 sub-lanes per
// query, padded LDS (stride 513), branchy insert, lexicographic merge.
__global__ __launch_bounds__(256) void knn_kernel(
    const float* __restrict__ xyz1, const float* __restrict__ xyz2,
    int* __restrict__ idx_out, float* __restrict__ w_out)
{
    __shared__ float4 sref[N2B + 4];         // padded: pos = p + p/512
    const int tid = threadIdx.x;
    const int qbase = blockIdx.x * 64;       // 1024 blocks x 64 queries
    const int batch = qbase / N1B;
    const float* k2 = xyz2 + (size_t)batch * N2B * 3;
    for (int p = tid; p < N2B; p += 256) {
        float x = k2[3 * p], y = k2[3 * p + 1], z = k2[3 * p + 2];
        float kk = add_rn(add_rn(mul_rn(x, x), mul_rn(y, y)), mul_rn(z, z));
        sref[p + (p >> 9)] = make_float4(x, y, z, kk);
    }
    __syncthreads();

    const int q = qbase + (tid >> 2);
    const int sub = tid & 3;
    const float qx = xyz1[q * 3 + 0], qy = xyz1[q * 3 + 1], qz = xyz1[q * 3 + 2];
    const float qq = add_rn(add_rn(mul_rn(qx, qx), mul_rn(qy, qy)), mul_rn(qz, qz));

    const int base = sub * 513;              // padded LDS base
    const int gbase = sub * 512;             // global index base
    float a0 = 1e30f, a1 = 1e30f, a2 = 1e30f;
    int   ai0 = 0x7fffffff, ai1 = 0x7fffffff, ai2 = 0x7fffffff;
    float c0 = 1e30f, c1 = 1e30f, c2 = 1e30f;
    int   ci0 = 0x7fffffff, ci1 = 0x7fffffff, ci2 = 0x7fffffff;
    for (int jj = 0; jj < 256; ++jj) {
        float4 rA = sref[base + jj];
        float4 rB = sref[base + 256 + jj];
        float pA = mul_rn(qx, rA.x);
        float tA = fma_rn(qz, rA.z, fma_rn(qy, rA.y, pA));
        float dA = add_rn(sub_rn(qq, add_rn(tA, tA)), rA.w);
        float pB = mul_rn(qx, rB.x);
        float tB = fma_rn(qz, rB.z, fma_rn(qy, rB.y, pB));
        float dB = add_rn(sub_rn(qq, add_rn(tB, tB)), rB.w);
        if (dA < a2) {
            if (dA < a1) {
                a2 = a1; ai2 = ai1;
                if (dA < a0) { a1 = a0; ai1 = ai0; a0 = dA; ai0 = gbase + jj; }
                else         { a1 = dA; ai1 = gbase + jj; }
            } else { a2 = dA; ai2 = gbase + jj; }
        }
        if (dB < c2) {
            if (dB < c1) {
                c2 = c1; ci2 = ci1;
                if (dB < c0) { c1 = c0; ci1 = ci0; c0 = dB; ci0 = gbase + 256 + jj; }
                else         { c1 = dB; ci1 = gbase + 256 + jj; }
            } else { c2 = dB; ci2 = gbase + 256 + jj; }
        }
    }
    float bd0 = a0, bd1 = a1, bd2 = a2;
    int   bi0 = ai0, bi1 = ai1, bi2 = ai2;
#define LEXINS(d, ji)                                                        \
    if ((d < bd2) || (d == bd2 && ji < bi2)) {                               \
        if ((d < bd1) || (d == bd1 && ji < bi1)) {                           \
            bd2 = bd1; bi2 = bi1;                                            \
            if ((d < bd0) || (d == bd0 && ji < bi0)) {                       \
                bd1 = bd0; bi1 = bi0; bd0 = d; bi0 = ji;                     \
            } else { bd1 = d; bi1 = ji; }                                    \
        } else { bd2 = d; bi2 = ji; }                                        \
    }
    LEXINS(c0, ci0) LEXINS(c1, ci1) LEXINS(c2, ci2)
#pragma unroll
    for (int mask = 1; mask <= 2; mask <<= 1) {
        float pd0 = __shfl_xor(bd0, mask, 64);
        float pd1 = __shfl_xor(bd1, mask, 64);
        float pd2 = __shfl_xor(bd2, mask, 64);
        int   pi0 = __shfl_xor(bi0, mask, 64);
        int   pi1 = __shfl_xor(bi1, mask, 64);
        int   pi2 = __shfl_xor(bi2, mask, 64);
        LEXINS(pd0, pi0) LEXINS(pd1, pi1) LEXINS(pd2, pi2)
    }
#undef LEXINS
    if (sub == 0) {
        float d0s = __fsqrt_rn(fmaxf(bd0, 0.0f));
        float d1s = __fsqrt_rn(fmaxf(bd1, 0.0f));
        float d2s = __fsqrt_rn(fmaxf(bd2, 0.0f));
        float r0 = __fdiv_rn(1.0f, add_rn(d0s, 1e-8f));
        float r1 = __fdiv_rn(1.0f, add_rn(d1s, 1e-8f));
        float r2 = __fdiv_rn(1.0f, add_rn(d2s, 1e-8f));
        float rs = add_rn(add_rn(r0, r1), r2);
        w_out[q * 3 + 0] = __fdiv_rn(r0, rs);
        w_out[q * 3 + 1] = __fdiv_rn(r1, rs);
        w_out[q * 3 + 2] = __fdiv_rn(r2, rs);
        idx_out[q * 3 + 0] = batch * N2B + bi0;
        idx_out[q * 3 + 1] = batch * N2B + bi1;
        idx_out[q * 3 + 2] = batch * N2B + bi2;
    }
}

// ------------------------------------------------------ prep kernels
// points2 f32 -> bf16 flat
__global__ __launch_bounds__(256) void cast_p2_kernel(
    const float* __restrict__ p2, short* __restrict__ p2b)
{
    const size_t i = ((size_t)blockIdx.x * 256 + threadIdx.x) * 8;
    float4 u0 = *(const float4*)(p2 + i);
    float4 u1 = *(const float4*)(p2 + i + 4);
    bf16x8 v;
    v[0] = f2bf(u0.x); v[1] = f2bf(u0.y); v[2] = f2bf(u0.z); v[3] = f2bf(u0.w);
    v[4] = f2bf(u1.x); v[5] = f2bf(u1.y); v[6] = f2bf(u1.z); v[7] = f2bf(u1.w);
    *(bf16x8*)(p2b + i) = v;
}

// W[K][N] f32 -> WT[N][K] bf16
__global__ __launch_bounds__(256) void transpose_w_kernel(
    const float* __restrict__ Win, short* __restrict__ WT, int K, int N)
{
    const int e = blockIdx.x * 256 + threadIdx.x;
    const int k = e / N, n = e % N;
    WT[(size_t)n * K + k] = f2bf(Win[e]);
}

// --------------------------------------------- bf16 MFMA GEMMs (128x128 tile)
#define LDP 40

#define GEMM_EPILOGUE(STORE_STMT)                                             \
    __shared__ float redS[2][2][64], redQ[2][2][64];                          \
    _Pragma("unroll")                                                         \
    for (int n = 0; n < 4; ++n) {                                             \
        const int col = col0 + wc * 64 + n * 16 + l16;                        \
        const float bv = bias[col];                                           \
        float s = 0.f, qa = 0.f;                                              \
        _Pragma("unroll")                                                     \
        for (int m = 0; m < 4; ++m) {                                         \
            const int rowb = row0 + wr * 64 + m * 16 + (lane >> 4) * 4;       \
            _Pragma("unroll")                                                 \
            for (int j = 0; j < 4; ++j) {                                     \
                float v = acc[m][n][j] + bv;                                  \
                STORE_STMT;                                                   \
                s += v; qa = fmaf(v, v, qa);                                  \
            }                                                                 \
        }                                                                     \
        s += __shfl_xor(s, 16, 64);  s += __shfl_xor(s, 32, 64);              \
        qa += __shfl_xor(qa, 16, 64); qa += __shfl_xor(qa, 32, 64);           \
        if ((lane >> 4) == 0) {                                               \
            redS[wr][wc][n * 16 + l16] = s;                                   \
            redQ[wr][wc][n * 16 + l16] = qa;                                  \
        }                                                                     \
    }                                                                         \
    __syncthreads();                                                          \
    if (tid < 128) {                                                          \
        const int wcf = tid >> 6, cf = tid & 63;                              \
        float s = redS[0][wcf][cf] + redS[1][wcf][cf];                        \
        float qa = redQ[0][wcf][cf] + redQ[1][wcf][cf];                       \
        const int gcol = col0 + wcf * 64 + cf;                                \
        psum[(size_t)blockIdx.y * HID + gcol] = s;                            \
        psq[(size_t)blockIdx.y * HID + gcol] = qa;                            \
    }

// y1b = bf16( [cast(points1) | interp] @ W1 + b1 ) — A built in staging:
//   cols <256: points1 f32 -> bf16 in-flight
//   cols >=256: 3-row gather of p2b (L2-resident) + IDW combine (same
//   fmaf-chain arithmetic as the r14/r15 interp kernel that passed)
__global__ __launch_bounds__(256) void gemm1m_kernel(
    const float* __restrict__ points1, const short* __restrict__ p2b,
    const int* __restrict__ idx, const float* __restrict__ w,
    const short* __restrict__ w1t, const float* __restrict__ bias,
    short* __restrict__ y1b, float* __restrict__ psum, float* __restrict__ psq)
{
    __shared__ short As[128][LDP];
    __shared__ short Bs[128][LDP];
    const int tid = threadIdx.x;
    const int lane = tid & 63, wv = tid >> 6;
    const int wr = wv >> 1, wc = wv & 1;
    const int l16 = lane & 15, kh = (lane >> 4) * 8;
    const int row0 = blockIdx.y * 128, col0 = blockIdx.x * 128;
    f32x4 acc[4][4];
#pragma unroll
    for (int m = 0; m < 4; ++m)
#pragma unroll
        for (int n = 0; n < 4; ++n) acc[m][n] = (f32x4){0.f, 0.f, 0.f, 0.f};

    const int c0 = tid * 2;
    const int r0c = c0 >> 2, kc0 = (c0 & 3) * 8;
    const int r1c = (c0 + 1) >> 2, kc1 = ((c0 + 1) & 3) * 8;

    // hoist kt-invariant gather indices/weights for this thread's two A-rows
    const int   rowA = row0 + r0c,        rowB = row0 + r1c;
    const int   jA0 = idx[rowA * 3 + 0], jA1 = idx[rowA * 3 + 1], jA2 = idx[rowA * 3 + 2];
    const float wA0 = w[rowA * 3 + 0],   wA1 = w[rowA * 3 + 1],   wA2 = w[rowA * 3 + 2];
    const int   jB0 = idx[rowB * 3 + 0], jB1 = idx[rowB * 3 + 1], jB2 = idx[rowB * 3 + 2];
    const float wB0 = w[rowB * 3 + 0],   wB1 = w[rowB * 3 + 1],   wB2 = w[rowB * 3 + 2];

    for (int kt = 0; kt < K1 / 32; ++kt) {
        const int k0 = kt * 32;
        bf16x8 va, vb;
        if (k0 < C1) {
            float4 u0 = *(const float4*)(points1 + (size_t)rowA * C1 + k0 + kc0);
            float4 u1 = *(const float4*)(points1 + (size_t)rowA * C1 + k0 + kc0 + 4);
            va[0] = f2bf(u0.x); va[1] = f2bf(u0.y); va[2] = f2bf(u0.z); va[3] = f2bf(u0.w);
            va[4] = f2bf(u1.x); va[5] = f2bf(u1.y); va[6] = f2bf(u1.z); va[7] = f2bf(u1.w);
            float4 u2 = *(const float4*)(points1 + (size_t)rowB * C1 + k0 + kc1);
            float4 u3 = *(const float4*)(points1 + (size_t)rowB * C1 + k0 + kc1 + 4);
            vb[0] = f2bf(u2.x); vb[1] = f2bf(u2.y); vb[2] = f2bf(u2.z); vb[3] = f2bf(u2.w);
            vb[4] = f2bf(u3.x); vb[5] = f2bf(u3.y); vb[6] = f2bf(u3.z); vb[7] = f2bf(u3.w);
        } else {
            const int kbA = k0 - C1 + kc0, kbB = k0 - C1 + kc1;
            bf16x8 ga = *(const bf16x8*)(p2b + (size_t)jA0 * C2 + kbA);
            bf16x8 gb = *(const bf16x8*)(p2b + (size_t)jA1 * C2 + kbA);
            bf16x8 gc = *(const bf16x8*)(p2b + (size_t)jA2 * C2 + kbA);
#pragma unroll
            for (int e = 0; e < 8; ++e)
                va[e] = f2bf(fmaf(bf2f(ga[e]), wA0,
                         fmaf(bf2f(gb[e]), wA1, bf2f(gc[e]) * wA2)));
            bf16x8 gd = *(const bf16x8*)(p2b + (size_t)jB0 * C2 + kbB);
            bf16x8 ge = *(const bf16x8*)(p2b + (size_t)jB1 * C2 + kbB);
            bf16x8 gf = *(const bf16x8*)(p2b + (size_t)jB2 * C2 + kbB);
#pragma unroll
            for (int e = 0; e < 8; ++e)
                vb[e] = f2bf(fmaf(bf2f(gd[e]), wB0,
                         fmaf(bf2f(ge[e]), wB1, bf2f(gf[e]) * wB2)));
        }
        bf16x8 wa = *(const bf16x8*)(w1t + (size_t)(col0 + r0c) * K1 + k0 + kc0);
        bf16x8 wb = *(const bf16x8*)(w1t + (size_t)(col0 + r1c) * K1 + k0 + kc1);
        __syncthreads();
        *(bf16x8*)(&As[r0c][kc0]) = va;
        *(bf16x8*)(&As[r1c][kc1]) = vb;
        *(bf16x8*)(&Bs[r0c][kc0]) = wa;
        *(bf16x8*)(&Bs[r1c][kc1]) = wb;
        __syncthreads();

        bf16x8 af[4], bf[4];
#pragma unroll
        for (int m = 0; m < 4; ++m)
            af[m] = *(const bf16x8*)(&As[wr * 64 + m * 16 + l16][kh]);
#pragma unroll
        for (int n = 0; n < 4; ++n)
            bf[n] = *(const bf16x8*)(&Bs[wc * 64 + n * 16 + l16][kh]);
#pragma unroll
        for (int m = 0; m < 4; ++m)
#pragma unroll
            for (int n = 0; n < 4; ++n)
                acc[m][n] = __builtin_amdgcn_mfma_f32_16x16x32_bf16(
                    af[m], bf[n], acc[m][n], 0, 0, 0);
    }
    GEMM_EPILOGUE(y1b[(size_t)(rowb + j) * HID + col] = f2bf(v))
}

// y2b = bf16( relu(bn(y1b)) @ W2 + b2 ), stats from f32 acc
__global__ __launch_bounds__(256) void gemm2m_kernel(
    const short* __restrict__ y1b, const float* __restrict__ scale,
    const float* __restrict__ shift, const short* __restrict__ w2t,
    const float* __restrict__ bias, short* __restrict__ y2b,
    float* __restrict__ psum, float* __restrict__ psq)
{
    __shared__ short As[128][LDP];
    __shared__ short Bs[128][LDP];
    const int tid = threadIdx.x;
    const int lane = tid & 63, wv = tid >> 6;
    const int wr = wv >> 1, wc = wv & 1;
    const int l16 = lane & 15, kh = (lane >> 4) * 8;
    const int row0 = blockIdx.y * 128, col0 = blockIdx.x * 128;
    f32x4 acc[4][4];
#pragma unroll
    for (int m = 0; m < 4; ++m)
#pragma unroll
        for (int n = 0; n < 4; ++n) acc[m][n] = (f32x4){0.f, 0.f, 0.f, 0.f};

    const int c0 = tid * 2;
    const int r0c = c0 >> 2, kc0 = (c0 & 3) * 8;
    const int r1c = (c0 + 1) >> 2, kc1 = ((c0 + 1) & 3) * 8;

    for (int kt = 0; kt < HID / 32; ++kt) {
        const int k0 = kt * 32;
        bf16x8 x0 = *(const bf16x8*)(y1b + (size_t)(row0 + r0c) * HID + k0 + kc0);
        bf16x8 x1 = *(const bf16x8*)(y1b + (size_t)(row0 + r1c) * HID + k0 + kc1);
        float4 s0 = *(const float4*)(scale + k0 + kc0);
        float4 s1 = *(const float4*)(scale + k0 + kc0 + 4);
        float4 h0 = *(const float4*)(shift + k0 + kc0);
        float4 h1 = *(const float4*)(shift + k0 + kc0 + 4);
        float4 s2 = *(const float4*)(scale + k0 + kc1);
        float4 s3 = *(const float4*)(scale + k0 + kc1 + 4);
        float4 h2 = *(const float4*)(shift + k0 + kc1);
        float4 h3 = *(const float4*)(shift + k0 + kc1 + 4);
        bf16x8 va, vb;
        va[0] = f2bf(fmaxf(fmaf(bf2f(x0[0]), s0.x, h0.x), 0.f));
        va[1] = f2bf(fmaxf(fmaf(bf2f(x0[1]), s0.y, h0.y), 0.f));
        va[2] = f2bf(fmaxf(fmaf(bf2f(x0[2]), s0.z, h0.z), 0.f));
        va[3] = f2bf(fmaxf(fmaf(bf2f(x0[3]), s0.w, h0.w), 0.f));
        va[4] = f2bf(fmaxf(fmaf(bf2f(x0[4]), s1.x, h1.x), 0.f));
        va[5] = f2bf(fmaxf(fmaf(bf2f(x0[5]), s1.y, h1.y), 0.f));
        va[6] = f2bf(fmaxf(fmaf(bf2f(x0[6]), s1.z, h1.z), 0.f));
        va[7] = f2bf(fmaxf(fmaf(bf2f(x0[7]), s1.w, h1.w), 0.f));
        vb[0] = f2bf(fmaxf(fmaf(bf2f(x1[0]), s2.x, h2.x), 0.f));
        vb[1] = f2bf(fmaxf(fmaf(bf2f(x1[1]), s2.y, h2.y), 0.f));
        vb[2] = f2bf(fmaxf(fmaf(bf2f(x1[2]), s2.z, h2.z), 0.f));
        vb[3] = f2bf(fmaxf(fmaf(bf2f(x1[3]), s2.w, h2.w), 0.f));
        vb[4] = f2bf(fmaxf(fmaf(bf2f(x1[4]), s3.x, h3.x), 0.f));
        vb[5] = f2bf(fmaxf(fmaf(bf2f(x1[5]), s3.y, h3.y), 0.f));
        vb[6] = f2bf(fmaxf(fmaf(bf2f(x1[6]), s3.z, h3.z), 0.f));
        vb[7] = f2bf(fmaxf(fmaf(bf2f(x1[7]), s3.w, h3.w), 0.f));
        bf16x8 wa = *(const bf16x8*)(w2t + (size_t)(col0 + r0c) * HID + k0 + kc0);
        bf16x8 wb = *(const bf16x8*)(w2t + (size_t)(col0 + r1c) * HID + k0 + kc1);
        __syncthreads();
        *(bf16x8*)(&As[r0c][kc0]) = va;
        *(bf16x8*)(&As[r1c][kc1]) = vb;
        *(bf16x8*)(&Bs[r0c][kc0]) = wa;
        *(bf16x8*)(&Bs[r1c][kc1]) = wb;
        __syncthreads();

        bf16x8 af[4], bf[4];
#pragma unroll
        for (int m = 0; m < 4; ++m)
            af[m] = *(const bf16x8*)(&As[wr * 64 + m * 16 + l16][kh]);
#pragma unroll
        for (int n = 0; n < 4; ++n)
            bf[n] = *(const bf16x8*)(&Bs[wc * 64 + n * 16 + l16][kh]);
#pragma unroll
        for (int m = 0; m < 4; ++m)
#pragma unroll
            for (int n = 0; n < 4; ++n)
                acc[m][n] = __builtin_amdgcn_mfma_f32_16x16x32_bf16(
                    af[m], bf[n], acc[m][n], 0, 0, 0);
    }
    GEMM_EPILOGUE(y2b[(size_t)(rowb + j) * HID + col] = f2bf(v))
}

// ----------------------------------------------------- BN finalize (512 rows)
__global__ __launch_bounds__(256) void bn_finalize_kernel(
    const float* __restrict__ psum, const float* __restrict__ psq,
    const float* __restrict__ g, const float* __restrict__ be,
    float* __restrict__ scale, float* __restrict__ shift)
{
    const int c = threadIdx.x;
    float s = 0.0f, q = 0.0f;
    for (int b = 0; b < 512; ++b) { s += psum[b * HID + c]; q += psq[b * HID + c]; }
    const float inv_n = 1.0f / (float)N1T;
    const float mu = s * inv_n;
    const float var = fmaxf(q * inv_n - mu * mu, 0.0f);
    const float sc = g[c] * rsqrtf(var + BN_EPS);
    scale[c] = sc;
    shift[c] = be[c] - mu * sc;
}

// --------------------------------------------------------- final BN+ReLU
__global__ __launch_bounds__(256) void bn_apply_kernel(
    const short* __restrict__ y2b, const float* __restrict__ scale,
    const float* __restrict__ shift, float* __restrict__ out)
{
    const size_t i = ((size_t)blockIdx.x * 256 + threadIdx.x) * 8;
    const int c8 = (int)(i & 255);
    bf16x8 x = *(const bf16x8*)(y2b + i);
    float4 s0 = *(const float4*)(scale + c8);
    float4 s1 = *(const float4*)(scale + c8 + 4);
    float4 h0 = *(const float4*)(shift + c8);
    float4 h1 = *(const float4*)(shift + c8 + 4);
    float4 o0, o1;
    o0.x = fmaxf(fmaf(bf2f(x[0]), s0.x, h0.x), 0.f);
    o0.y = fmaxf(fmaf(bf2f(x[1]), s0.y, h0.y), 0.f);
    o0.z = fmaxf(fmaf(bf2f(x[2]), s0.z, h0.z), 0.f);
    o0.w = fmaxf(fmaf(bf2f(x[3]), s0.w, h0.w), 0.f);
    o1.x = fmaxf(fmaf(bf2f(x[4]), s1.x, h1.x), 0.f);
    o1.y = fmaxf(fmaf(bf2f(x[5]), s1.y, h1.y), 0.f);
    o1.z = fmaxf(fmaf(bf2f(x[6]), s1.z, h1.z), 0.f);
    o1.w = fmaxf(fmaf(bf2f(x[7]), s1.w, h1.w), 0.f);
    *(float4*)(out + i) = o0;
    *(float4*)(out + i + 4) = o1;
}

// -------------------------------------------------------------- launcher
extern "C" void kernel_launch(void* const* d_in, const int* in_sizes, int n_in,
                              void* d_out, int out_size, void* d_ws, size_t ws_size,
                              hipStream_t stream)
{
    const float* xyz1    = (const float*)d_in[0];
    const float* points1 = (const float*)d_in[1];
    const float* xyz2    = (const float*)d_in[2];
    const float* points2 = (const float*)d_in[3];
    const float* W1  = (const float*)d_in[6];
    const float* b1  = (const float*)d_in[7];
    const float* g1  = (const float*)d_in[8];
    const float* be1 = (const float*)d_in[9];
    const float* W2  = (const float*)d_in[10];
    const float* b2  = (const float*)d_in[11];
    const float* g2  = (const float*)d_in[12];
    const float* be2 = (const float*)d_in[13];
    float* out = (float*)d_out;

    char* ws = (char*)d_ws;
    short* y1b  = (short*)ws;                          // bf16 [N1][256]
    short* y2b  = (short*)(ws + 33554432);             // bf16 [N1][256]
    short* p2b  = (short*)(ws + 67108864);             // bf16 [N2T][512]
    size_t off  = 67108864 + 16777216;
    short*  w1t    = (short*)(ws + off);  off += (size_t)K1 * HID * 2;
    short*  w2t    = (short*)(ws + off);  off += (size_t)HID * HID * 2;
    int*    idx    = (int*)(ws + off);    off += (size_t)N1T * 3 * 4;
    float*  w      = (float*)(ws + off);  off += (size_t)N1T * 3 * 4;
    float*  psum   = (float*)(ws + off);  off += 512 * 256 * 4;
    float*  psq    = (float*)(ws + off);  off += 512 * 256 * 4;
    float*  scale1 = (float*)(ws + off);  off += 256 * 4;
    float*  shift1 = (float*)(ws + off);  off += 256 * 4;
    float*  scale2 = (float*)(ws + off);  off += 256 * 4;
    float*  shift2 = (float*)(ws + off);  off += 256 * 4;

    cast_p2_kernel<<<N2T * C2 / 8 / 256, 256, 0, stream>>>(points2, p2b);
    transpose_w_kernel<<<K1 * HID / 256, 256, 0, stream>>>(W1, w1t, K1, HID);
    transpose_w_kernel<<<HID * HID / 256, 256, 0, stream>>>(W2, w2t, HID, HID);
    knn_kernel<<<1024, 256, 0, stream>>>(xyz1, xyz2, idx, w);
    gemm1m_kernel<<<dim3(HID / 128, N1T / 128), 256, 0, stream>>>(
        points1, p2b, idx, w, w1t, b1, y1b, psum, psq);
    bn_finalize_kernel<<<1, 256, 0, stream>>>(psum, psq, g1, be1, scale1, shift1);
    gemm2m_kernel<<<dim3(HID / 128, N1T / 128), 256, 0, stream>>>(
        y1b, scale1, shift1, w2t, b2, y2b, psum, psq);
    bn_finalize_kernel<<<1, 256, 0, stream>>>(psum, psq, g2, be2, scale2, shift2);
    bn_apply_kernel<<<N1T * HID / 8 / 256, 256, 0, stream>>>(y2b, scale2, shift2, out);
}

// Round 17
// 233.292 us; speedup vs baseline: 1.2849x; 1.1765x over previous
//
#include <hip/hip_runtime.h>
#include <math.h>

#define N1T 65536
#define N2T 16384
#define BSZ 8
#define N1B 8192   // points per batch in xyz1
#define N2B 2048   // points per batch in xyz2
#define C1 256
#define C2 512
#define K1 768     // C1 + C2
#define HID 256
#define BN_EPS 1e-5f

typedef short bf16x8 __attribute__((ext_vector_type(8)));
typedef float f32x4 __attribute__((ext_vector_type(4)));

// Exact single-rounded f32 ops via ISA — immune to -ffast-math / contraction.
__device__ __forceinline__ float mul_rn(float a, float b) {
    float r; asm("v_mul_f32 %0, %1, %2" : "=v"(r) : "v"(a), "v"(b)); return r;
}
__device__ __forceinline__ float add_rn(float a, float b) {
    float r; asm("v_add_f32 %0, %1, %2" : "=v"(r) : "v"(a), "v"(b)); return r;
}
__device__ __forceinline__ float sub_rn(float a, float b) {
    float r; asm("v_sub_f32 %0, %1, %2" : "=v"(r) : "v"(a), "v"(b)); return r;
}
__device__ __forceinline__ float fma_rn(float a, float b, float c) {
    float r; asm("v_fma_f32 %0, %1, %2, %3" : "=v"(r) : "v"(a), "v"(b), "v"(c)); return r;
}
// f32 -> bf16 round-to-nearest-even
__device__ __forceinline__ short f2bf(float f) {
    unsigned u = __builtin_bit_cast(unsigned, f);
    u += 0x7fffu + ((u >> 16) & 1u);
    return (short)(u >> 16);
}
// bf16 -> f32 (exact)
__device__ __forceinline__ float bf2f(short s) {
    return __builtin_bit_cast(float, ((unsigned)(unsigned short)s) << 16);
}

// ---------------------------------------------------------------- KNN-3
// FROZEN: r13's kernel verbatim — best measured (72.3 µs).
__global__ __launch_bounds__(256) void knn_kernel(
    const float* __restrict__ xyz1, const float* __restrict__ xyz2,
    int* __restrict__ idx_out, float* __restrict__ w_out)
{
    __shared__ float4 sref[N2B + 4];         // padded: pos = p + p/512
    const int tid = threadIdx.x;
    const int qbase = blockIdx.x * 64;       // 1024 blocks x 64 queries
    const int batch = qbase / N1B;
    const float* k2 = xyz2 + (size_t)batch * N2B * 3;
    for (int p = tid; p < N2B; p += 256) {
        float x = k2[3 * p], y = k2[3 * p + 1], z = k2[3 * p + 2];
        float kk = add_rn(add_rn(mul_rn(x, x), mul_rn(y, y)), mul_rn(z, z));
        sref[p + (p >> 9)] = make_float4(x, y, z, kk);
    }
    __syncthreads();

    const int q = qbase + (tid >> 2);
    const int sub = tid & 3;
    const float qx = xyz1[q * 3 + 0], qy = xyz1[q * 3 + 1], qz = xyz1[q * 3 + 2];
    const float qq = add_rn(add_rn(mul_rn(qx, qx), mul_rn(qy, qy)), mul_rn(qz, qz));

    const int base = sub * 513;              // padded LDS base
    const int gbase = sub * 512;             // global index base
    float a0 = 1e30f, a1 = 1e30f, a2 = 1e30f;
    int   ai0 = 0x7fffffff, ai1 = 0x7fffffff, ai2 = 0x7fffffff;
    float c0 = 1e30f, c1 = 1e30f, c2 = 1e30f;
    int   ci0 = 0x7fffffff, ci1 = 0x7fffffff, ci2 = 0x7fffffff;
    for (int jj = 0; jj < 256; ++jj) {
        float4 rA = sref[base + jj];
        float4 rB = sref[base + 256 + jj];
        float pA = mul_rn(qx, rA.x);
        float tA = fma_rn(qz, rA.z, fma_rn(qy, rA.y, pA));
        float dA = add_rn(sub_rn(qq, add_rn(tA, tA)), rA.w);
        float pB = mul_rn(qx, rB.x);
        float tB = fma_rn(qz, rB.z, fma_rn(qy, rB.y, pB));
        float dB = add_rn(sub_rn(qq, add_rn(tB, tB)), rB.w);
        if (dA < a2) {
            if (dA < a1) {
                a2 = a1; ai2 = ai1;
                if (dA < a0) { a1 = a0; ai1 = ai0; a0 = dA; ai0 = gbase + jj; }
                else         { a1 = dA; ai1 = gbase + jj; }
            } else { a2 = dA; ai2 = gbase + jj; }
        }
        if (dB < c2) {
            if (dB < c1) {
                c2 = c1; ci2 = ci1;
                if (dB < c0) { c1 = c0; ci1 = ci0; c0 = dB; ci0 = gbase + 256 + jj; }
                else         { c1 = dB; ci1 = gbase + 256 + jj; }
            } else { c2 = dB; ci2 = gbase + 256 + jj; }
        }
    }
    float bd0 = a0, bd1 = a1, bd2 = a2;
    int   bi0 = ai0, bi1 = ai1, bi2 = ai2;
#define LEXINS(d, ji)                                                        \
    if ((d < bd2) || (d == bd2 && ji < bi2)) {                               \
        if ((d < bd1) || (d == bd1 && ji < bi1)) {                           \
            bd2 = bd1; bi2 = bi1;                                            \
            if ((d < bd0) || (d == bd0 && ji < bi0)) {                       \
                bd1 = bd0; bi1 = bi0; bd0 = d; bi0 = ji;                     \
            } else { bd1 = d; bi1 = ji; }                                    \
        } else { bd2 = d; bi2 = ji; }                                        \
    }
    LEXINS(c0, ci0) LEXINS(c1, ci1) LEXINS(c2, ci2)
#pragma unroll
    for (int mask = 1; mask <= 2; mask <<= 1) {
        float pd0 = __shfl_xor(bd0, mask, 64);
        float pd1 = __shfl_xor(bd1, mask, 64);
        float pd2 = __shfl_xor(bd2, mask, 64);
        int   pi0 = __shfl_xor(bi0, mask, 64);
        int   pi1 = __shfl_xor(bi1, mask, 64);
        int   pi2 = __shfl_xor(bi2, mask, 64);
        LEXINS(pd0, pi0) LEXINS(pd1, pi1) LEXINS(pd2, pi2)
    }
#undef LEXINS
    if (sub == 0) {
        float d0s = __fsqrt_rn(fmaxf(bd0, 0.0f));
        float d1s = __fsqrt_rn(fmaxf(bd1, 0.0f));
        float d2s = __fsqrt_rn(fmaxf(bd2, 0.0f));
        float r0 = __fdiv_rn(1.0f, add_rn(d0s, 1e-8f));
        float r1 = __fdiv_rn(1.0f, add_rn(d1s, 1e-8f));
        float r2 = __fdiv_rn(1.0f, add_rn(d2s, 1e-8f));
        float rs = add_rn(add_rn(r0, r1), r2);
        w_out[q * 3 + 0] = __fdiv_rn(r0, rs);
        w_out[q * 3 + 1] = __fdiv_rn(r1, rs);
        w_out[q * 3 + 2] = __fdiv_rn(r2, rs);
        idx_out[q * 3 + 0] = batch * N2B + bi0;
        idx_out[q * 3 + 1] = batch * N2B + bi1;
        idx_out[q * 3 + 2] = batch * N2B + bi2;
    }
}

// ------------------------------------------------------ prep kernels
__global__ __launch_bounds__(256) void cast_p2_kernel(
    const float* __restrict__ p2, short* __restrict__ p2b)
{
    const size_t i = ((size_t)blockIdx.x * 256 + threadIdx.x) * 8;
    float4 u0 = *(const float4*)(p2 + i);
    float4 u1 = *(const float4*)(p2 + i + 4);
    bf16x8 v;
    v[0] = f2bf(u0.x); v[1] = f2bf(u0.y); v[2] = f2bf(u0.z); v[3] = f2bf(u0.w);
    v[4] = f2bf(u1.x); v[5] = f2bf(u1.y); v[6] = f2bf(u1.z); v[7] = f2bf(u1.w);
    *(bf16x8*)(p2b + i) = v;
}

__global__ __launch_bounds__(256) void transpose_w_kernel(
    const float* __restrict__ Win, short* __restrict__ WT, int K, int N)
{
    const int e = blockIdx.x * 256 + threadIdx.x;
    const int k = e / N, n = e % N;
    WT[(size_t)n * K + k] = f2bf(Win[e]);
}

// --------------------------------------------- bf16 MFMA GEMMs
#define LDP 40

// ============ gemm1m: 8-wave 128x256 tile, single-pass A build, prefetch ====
// y1b = bf16( [cast(points1) | interp] @ W1 + b1 )
// A built in staging (once per row-block): cols <256 points1 f32->bf16;
// cols >=256 3-row p2b gather + IDW (identical fmaf-chain arithmetic).
// One-deep register prefetch hides gather latency under MFMA.
__global__ __launch_bounds__(512) void gemm1m_kernel(
    const float* __restrict__ points1, const short* __restrict__ p2b,
    const int* __restrict__ idx, const float* __restrict__ w,
    const short* __restrict__ w1t, const float* __restrict__ bias,
    short* __restrict__ y1b, float* __restrict__ psum, float* __restrict__ psq)
{
    __shared__ short As[128][LDP];
    __shared__ short Bs[256][LDP];
    __shared__ float redS[2][4][64], redQ[2][4][64];
    const int tid = threadIdx.x;              // 0..511
    const int lane = tid & 63, wv = tid >> 6; // 8 waves
    const int wr = wv >> 2, wc = wv & 3;      // 2 x 4 wave grid (64x64 each)
    const int l16 = lane & 15, kh = (lane >> 4) * 8;
    const int row0 = blockIdx.x * 128;
    f32x4 acc[4][4];
#pragma unroll
    for (int m = 0; m < 4; ++m)
#pragma unroll
        for (int n = 0; n < 4; ++n) acc[m][n] = (f32x4){0.f, 0.f, 0.f, 0.f};

    // A staging: 1 chunk/thread. row = tid>>2, kc = (tid&3)*8
    const int arow = tid >> 2, akc = (tid & 3) * 8;
    const int rowA = row0 + arow;
    const int   jA0 = idx[rowA * 3 + 0], jA1 = idx[rowA * 3 + 1], jA2 = idx[rowA * 3 + 2];
    const float wA0 = w[rowA * 3 + 0],   wA1 = w[rowA * 3 + 1],   wA2 = w[rowA * 3 + 2];
    // B staging: 2 chunks/thread. cb = tid*2 + {0,1}; row = cb>>2, kc = (cb&3)*8
    const int cb0 = tid * 2, cb1 = tid * 2 + 1;
    const int brow0 = cb0 >> 2, bkc0 = (cb0 & 3) * 8;
    const int brow1 = cb1 >> 2, bkc1 = (cb1 & 3) * 8;

#define LOAD_A(VA, KT)                                                        \
    {                                                                         \
        const int k0_ = (KT) * 32;                                            \
        if (k0_ < C1) {                                                       \
            float4 u0 = *(const float4*)(points1 + (size_t)rowA * C1 + k0_ + akc);     \
            float4 u1 = *(const float4*)(points1 + (size_t)rowA * C1 + k0_ + akc + 4); \
            VA[0] = f2bf(u0.x); VA[1] = f2bf(u0.y); VA[2] = f2bf(u0.z); VA[3] = f2bf(u0.w); \
            VA[4] = f2bf(u1.x); VA[5] = f2bf(u1.y); VA[6] = f2bf(u1.z); VA[7] = f2bf(u1.w); \
        } else {                                                              \
            const int kb = k0_ - C1 + akc;                                    \
            bf16x8 ga = *(const bf16x8*)(p2b + (size_t)jA0 * C2 + kb);        \
            bf16x8 gb = *(const bf16x8*)(p2b + (size_t)jA1 * C2 + kb);        \
            bf16x8 gc = *(const bf16x8*)(p2b + (size_t)jA2 * C2 + kb);        \
            _Pragma("unroll")                                                 \
            for (int e = 0; e < 8; ++e)                                       \
                VA[e] = f2bf(fmaf(bf2f(ga[e]), wA0,                           \
                          fmaf(bf2f(gb[e]), wA1, bf2f(gc[e]) * wA2)));        \
        }                                                                     \
    }
#define LOAD_B(WA, WB, KT)                                                    \
    {                                                                         \
        const int k0_ = (KT) * 32;                                            \
        WA = *(const bf16x8*)(w1t + (size_t)brow0 * K1 + k0_ + bkc0);         \
        WB = *(const bf16x8*)(w1t + (size_t)brow1 * K1 + k0_ + bkc1);         \
    }

    bf16x8 va, wa, wb;
    LOAD_A(va, 0)
    LOAD_B(wa, wb, 0)
    for (int kt = 0; kt < K1 / 32; ++kt) {
        __syncthreads();                    // prev iter's ds_reads complete
        *(bf16x8*)(&As[arow][akc]) = va;
        *(bf16x8*)(&Bs[brow0][bkc0]) = wa;
        *(bf16x8*)(&Bs[brow1][bkc1]) = wb;
        __syncthreads();
        if (kt + 1 < K1 / 32) {             // prefetch next tile into regs
            LOAD_A(va, kt + 1)
            LOAD_B(wa, wb, kt + 1)
        }
        bf16x8 af[4], bf[4];
#pragma unroll
        for (int m = 0; m < 4; ++m)
            af[m] = *(const bf16x8*)(&As[wr * 64 + m * 16 + l16][kh]);
#pragma unroll
        for (int n = 0; n < 4; ++n)
            bf[n] = *(const bf16x8*)(&Bs[wc * 64 + n * 16 + l16][kh]);
#pragma unroll
        for (int m = 0; m < 4; ++m)
#pragma unroll
            for (int n = 0; n < 4; ++n)
                acc[m][n] = __builtin_amdgcn_mfma_f32_16x16x32_bf16(
                    af[m], bf[n], acc[m][n], 0, 0, 0);
    }
#undef LOAD_A
#undef LOAD_B
    // epilogue: bias, store bf16, BN partials
#pragma unroll
    for (int n = 0; n < 4; ++n) {
        const int col = wc * 64 + n * 16 + l16;
        const float bv = bias[col];
        float s = 0.f, qa = 0.f;
#pragma unroll
        for (int m = 0; m < 4; ++m) {
            const int rowb = row0 + wr * 64 + m * 16 + (lane >> 4) * 4;
#pragma unroll
            for (int j = 0; j < 4; ++j) {
                float v = acc[m][n][j] + bv;
                y1b[(size_t)(rowb + j) * HID + col] = f2bf(v);
                s += v; qa = fmaf(v, v, qa);
            }
        }
        s += __shfl_xor(s, 16, 64);  s += __shfl_xor(s, 32, 64);
        qa += __shfl_xor(qa, 16, 64); qa += __shfl_xor(qa, 32, 64);
        if ((lane >> 4) == 0) {
            redS[wr][wc][n * 16 + l16] = s;
            redQ[wr][wc][n * 16 + l16] = qa;
        }
    }
    __syncthreads();
    if (tid < 256) {
        const int wcf = tid >> 6, cf = tid & 63;
        float s = redS[0][wcf][cf] + redS[1][wcf][cf];
        float qa = redQ[0][wcf][cf] + redQ[1][wcf][cf];
        psum[(size_t)blockIdx.x * HID + tid] = s;
        psq[(size_t)blockIdx.x * HID + tid] = qa;
    }
}

// ============ gemm2m: unchanged r16 structure (128x128, 4 waves) ============
#define GEMM_EPILOGUE(STORE_STMT)                                             \
    __shared__ float redS[2][2][64], redQ[2][2][64];                          \
    _Pragma("unroll")                                                         \
    for (int n = 0; n < 4; ++n) {                                             \
        const int col = col0 + wc * 64 + n * 16 + l16;                        \
        const float bv = bias[col];                                           \
        float s = 0.f, qa = 0.f;                                              \
        _Pragma("unroll")                                                     \
        for (int m = 0; m < 4; ++m) {                                         \
            const int rowb = row0 + wr * 64 + m * 16 + (lane >> 4) * 4;       \
            _Pragma("unroll")                                                 \
            for (int j = 0; j < 4; ++j) {                                     \
                float v = acc[m][n][j] + bv;                                  \
                STORE_STMT;                                                   \
                s += v; qa = fmaf(v, v, qa);                                  \
            }                                                                 \
        }                                                                     \
        s += __shfl_xor(s, 16, 64);  s += __shfl_xor(s, 32, 64);              \
        qa += __shfl_xor(qa, 16, 64); qa += __shfl_xor(qa, 32, 64);           \
        if ((lane >> 4) == 0) {                                               \
            redS[wr][wc][n * 16 + l16] = s;                                   \
            redQ[wr][wc][n * 16 + l16] = qa;                                  \
        }                                                                     \
    }                                                                         \
    __syncthreads();                                                          \
    if (tid < 128) {                                                          \
        const int wcf = tid >> 6, cf = tid & 63;                              \
        float s = redS[0][wcf][cf] + redS[1][wcf][cf];                        \
        float qa = redQ[0][wcf][cf] + redQ[1][wcf][cf];                       \
        const int gcol = col0 + wcf * 64 + cf;                                \
        psum[(size_t)blockIdx.y * HID + gcol] = s;                            \
        psq[(size_t)blockIdx.y * HID + gcol] = qa;                            \
    }

// y2b = bf16( relu(bn(y1b)) @ W2 + b2 ), stats from f32 acc
__global__ __launch_bounds__(256) void gemm2m_kernel(
    const short* __restrict__ y1b, const float* __restrict__ scale,
    const float* __restrict__ shift, const short* __restrict__ w2t,
    const float* __restrict__ bias, short* __restrict__ y2b,
    float* __restrict__ psum, float* __restrict__ psq)
{
    __shared__ short As[128][LDP];
    __shared__ short Bs[128][LDP];
    const int tid = threadIdx.x;
    const int lane = tid & 63, wv = tid >> 6;
    const int wr = wv >> 1, wc = wv & 1;
    const int l16 = lane & 15, kh = (lane >> 4) * 8;
    const int row0 = blockIdx.y * 128, col0 = blockIdx.x * 128;
    f32x4 acc[4][4];
#pragma unroll
    for (int m = 0; m < 4; ++m)
#pragma unroll
        for (int n = 0; n < 4; ++n) acc[m][n] = (f32x4){0.f, 0.f, 0.f, 0.f};

    const int c0 = tid * 2;
    const int r0c = c0 >> 2, kc0 = (c0 & 3) * 8;
    const int r1c = (c0 + 1) >> 2, kc1 = ((c0 + 1) & 3) * 8;

    for (int kt = 0; kt < HID / 32; ++kt) {
        const int k0 = kt * 32;
        bf16x8 x0 = *(const bf16x8*)(y1b + (size_t)(row0 + r0c) * HID + k0 + kc0);
        bf16x8 x1 = *(const bf16x8*)(y1b + (size_t)(row0 + r1c) * HID + k0 + kc1);
        float4 s0 = *(const float4*)(scale + k0 + kc0);
        float4 s1 = *(const float4*)(scale + k0 + kc0 + 4);
        float4 h0 = *(const float4*)(shift + k0 + kc0);
        float4 h1 = *(const float4*)(shift + k0 + kc0 + 4);
        float4 s2 = *(const float4*)(scale + k0 + kc1);
        float4 s3 = *(const float4*)(scale + k0 + kc1 + 4);
        float4 h2 = *(const float4*)(shift + k0 + kc1);
        float4 h3 = *(const float4*)(shift + k0 + kc1 + 4);
        bf16x8 va, vb;
        va[0] = f2bf(fmaxf(fmaf(bf2f(x0[0]), s0.x, h0.x), 0.f));
        va[1] = f2bf(fmaxf(fmaf(bf2f(x0[1]), s0.y, h0.y), 0.f));
        va[2] = f2bf(fmaxf(fmaf(bf2f(x0[2]), s0.z, h0.z), 0.f));
        va[3] = f2bf(fmaxf(fmaf(bf2f(x0[3]), s0.w, h0.w), 0.f));
        va[4] = f2bf(fmaxf(fmaf(bf2f(x0[4]), s1.x, h1.x), 0.f));
        va[5] = f2bf(fmaxf(fmaf(bf2f(x0[5]), s1.y, h1.y), 0.f));
        va[6] = f2bf(fmaxf(fmaf(bf2f(x0[6]), s1.z, h1.z), 0.f));
        va[7] = f2bf(fmaxf(fmaf(bf2f(x0[7]), s1.w, h1.w), 0.f));
        vb[0] = f2bf(fmaxf(fmaf(bf2f(x1[0]), s2.x, h2.x), 0.f));
        vb[1] = f2bf(fmaxf(fmaf(bf2f(x1[1]), s2.y, h2.y), 0.f));
        vb[2] = f2bf(fmaxf(fmaf(bf2f(x1[2]), s2.z, h2.z), 0.f));
        vb[3] = f2bf(fmaxf(fmaf(bf2f(x1[3]), s2.w, h2.w), 0.f));
        vb[4] = f2bf(fmaxf(fmaf(bf2f(x1[4]), s3.x, h3.x), 0.f));
        vb[5] = f2bf(fmaxf(fmaf(bf2f(x1[5]), s3.y, h3.y), 0.f));
        vb[6] = f2bf(fmaxf(fmaf(bf2f(x1[6]), s3.z, h3.z), 0.f));
        vb[7] = f2bf(fmaxf(fmaf(bf2f(x1[7]), s3.w, h3.w), 0.f));
        bf16x8 wa = *(const bf16x8*)(w2t + (size_t)(col0 + r0c) * HID + k0 + kc0);
        bf16x8 wb = *(const bf16x8*)(w2t + (size_t)(col0 + r1c) * HID + k0 + kc1);
        __syncthreads();
        *(bf16x8*)(&As[r0c][kc0]) = va;
        *(bf16x8*)(&As[r1c][kc1]) = vb;
        *(bf16x8*)(&Bs[r0c][kc0]) = wa;
        *(bf16x8*)(&Bs[r1c][kc1]) = wb;
        __syncthreads();

        bf16x8 af[4], bf[4];
#pragma unroll
        for (int m = 0; m < 4; ++m)
            af[m] = *(const bf16x8*)(&As[wr * 64 + m * 16 + l16][kh]);
#pragma unroll
        for (int n = 0; n < 4; ++n)
            bf[n] = *(const bf16x8*)(&Bs[wc * 64 + n * 16 + l16][kh]);
#pragma unroll
        for (int m = 0; m < 4; ++m)
#pragma unroll
            for (int n = 0; n < 4; ++n)
                acc[m][n] = __builtin_amdgcn_mfma_f32_16x16x32_bf16(
                    af[m], bf[n], acc[m][n], 0, 0, 0);
    }
    GEMM_EPILOGUE(y2b[(size_t)(rowb + j) * HID + col] = f2bf(v))
}

// ----------------------------------------------------- BN finalize (512 rows)
__global__ __launch_bounds__(256) void bn_finalize_kernel(
    const float* __restrict__ psum, const float* __restrict__ psq,
    const float* __restrict__ g, const float* __restrict__ be,
    float* __restrict__ scale, float* __restrict__ shift)
{
    const int c = threadIdx.x;
    float s = 0.0f, q = 0.0f;
    for (int b = 0; b < 512; ++b) { s += psum[b * HID + c]; q += psq[b * HID + c]; }
    const float inv_n = 1.0f / (float)N1T;
    const float mu = s * inv_n;
    const float var = fmaxf(q * inv_n - mu * mu, 0.0f);
    const float sc = g[c] * rsqrtf(var + BN_EPS);
    scale[c] = sc;
    shift[c] = be[c] - mu * sc;
}

// --------------------------------------------------------- final BN+ReLU
__global__ __launch_bounds__(256) void bn_apply_kernel(
    const short* __restrict__ y2b, const float* __restrict__ scale,
    const float* __restrict__ shift, float* __restrict__ out)
{
    const size_t i = ((size_t)blockIdx.x * 256 + threadIdx.x) * 8;
    const int c8 = (int)(i & 255);
    bf16x8 x = *(const bf16x8*)(y2b + i);
    float4 s0 = *(const float4*)(scale + c8);
    float4 s1 = *(const float4*)(scale + c8 + 4);
    float4 h0 = *(const float4*)(shift + c8);
    float4 h1 = *(const float4*)(shift + c8 + 4);
    float4 o0, o1;
    o0.x = fmaxf(fmaf(bf2f(x[0]), s0.x, h0.x), 0.f);
    o0.y = fmaxf(fmaf(bf2f(x[1]), s0.y, h0.y), 0.f);
    o0.z = fmaxf(fmaf(bf2f(x[2]), s0.z, h0.z), 0.f);
    o0.w = fmaxf(fmaf(bf2f(x[3]), s0.w, h0.w), 0.f);
    o1.x = fmaxf(fmaf(bf2f(x[4]), s1.x, h1.x), 0.f);
    o1.y = fmaxf(fmaf(bf2f(x[5]), s1.y, h1.y), 0.f);
    o1.z = fmaxf(fmaf(bf2f(x[6]), s1.z, h1.z), 0.f);
    o1.w = fmaxf(fmaf(bf2f(x[7]), s1.w, h1.w), 0.f);
    *(float4*)(out + i) = o0;
    *(float4*)(out + i + 4) = o1;
}

// -------------------------------------------------------------- launcher
extern "C" void kernel_launch(void* const* d_in, const int* in_sizes, int n_in,
                              void* d_out, int out_size, void* d_ws, size_t ws_size,
                              hipStream_t stream)
{
    const float* xyz1    = (const float*)d_in[0];
    const float* points1 = (const float*)d_in[1];
    const float* xyz2    = (const float*)d_in[2];
    const float* points2 = (const float*)d_in[3];
    const float* W1  = (const float*)d_in[6];
    const float* b1  = (const float*)d_in[7];
    const float* g1  = (const float*)d_in[8];
    const float* be1 = (const float*)d_in[9];
    const float* W2  = (const float*)d_in[10];
    const float* b2  = (const float*)d_in[11];
    const float* g2  = (const float*)d_in[12];
    const float* be2 = (const float*)d_in[13];
    float* out = (float*)d_out;

    char* ws = (char*)d_ws;
    short* y1b  = (short*)ws;                          // bf16 [N1][256]
    short* y2b  = (short*)(ws + 33554432);             // bf16 [N1][256]
    short* p2b  = (short*)(ws + 67108864);             // bf16 [N2T][512]
    size_t off  = 67108864 + 16777216;
    short*  w1t    = (short*)(ws + off);  off += (size_t)K1 * HID * 2;
    short*  w2t    = (short*)(ws + off);  off += (size_t)HID * HID * 2;
    int*    idx    = (int*)(ws + off);    off += (size_t)N1T * 3 * 4;
    float*  w      = (float*)(ws + off);  off += (size_t)N1T * 3 * 4;
    float*  psum   = (float*)(ws + off);  off += 512 * 256 * 4;
    float*  psq    = (float*)(ws + off);  off += 512 * 256 * 4;
    float*  scale1 = (float*)(ws + off);  off += 256 * 4;
    float*  shift1 = (float*)(ws + off);  off += 256 * 4;
    float*  scale2 = (float*)(ws + off);  off += 256 * 4;
    float*  shift2 = (float*)(ws + off);  off += 256 * 4;

    cast_p2_kernel<<<N2T * C2 / 8 / 256, 256, 0, stream>>>(points2, p2b);
    transpose_w_kernel<<<K1 * HID / 256, 256, 0, stream>>>(W1, w1t, K1, HID);
    transpose_w_kernel<<<HID * HID / 256, 256, 0, stream>>>(W2, w2t, HID, HID);
    knn_kernel<<<1024, 256, 0, stream>>>(xyz1, xyz2, idx, w);
    gemm1m_kernel<<<N1T / 128, 512, 0, stream>>>(
        points1, p2b, idx, w, w1t, b1, y1b, psum, psq);
    bn_finalize_kernel<<<1, 256, 0, stream>>>(psum, psq, g1, be1, scale1, shift1);
    gemm2m_kernel<<<dim3(HID / 128, N1T / 128), 256, 0, stream>>>(
        y1b, scale1, shift1, w2t, b2, y2b, psum, psq);
    bn_finalize_kernel<<<1, 256, 0, stream>>>(psum, psq, g2, be2, scale2, shift2);
    bn_apply_kernel<<<N1T * HID / 8 / 256, 256, 0, stream>>>(y2b, scale2, shift2, out);
}